// Round 2
// baseline (239.323 us; speedup 1.0000x reference)
//
#include <hip/hip_runtime.h>
#include <math.h>

#define B_   32
#define N_   128
#define H_   100
#define ROWS (B_ * N_)    // 4096
#define RH   (ROWS * H_)  // 409600
#define OUTSZ (B_ * H_)   // 3200
#define RPB  8            // rows per block
#define RPT  4            // rows per thread (register tile)

// ---------------------------------------------------------------------------
// K1: hw = nodes@Ww ONLY (initial hv computed in-register by pass 1).
// Also zero-initializes out. 8 rows/block, 4 rows/thread: each Ww element
// load feeds 4 FMAs -> 4x less L1/L2 weight traffic than 2-rows/block.
__global__ __launch_bounds__(256, 2) void k_proj0(const float* __restrict__ nodes,
                                                  const float* __restrict__ Ww,
                                                  float* __restrict__ hw,
                                                  float* __restrict__ out) {
    __shared__ float nod_s[RPB][H_];
    const int bx = blockIdx.x;
    const int row0 = bx * RPB;
    const int t = threadIdx.x, rg = t >> 7, j = t & 127;
    {   // zero out[] (3 dispatches before any atomicAdd; stream-ordered)
        const int gid = bx * 256 + t;
        if (gid < OUTSZ) out[gid] = 0.f;
    }
    {
        const float4* ng = (const float4*)(nodes + (size_t)row0 * H_);
        if (t < 200) ((float4*)nod_s)[t] = ng[t];   // 8 rows x 25 float4
    }
    __syncthreads();
    if (j >= H_) return;
    float wa[RPT] = {0.f, 0.f, 0.f, 0.f};
#pragma unroll 5
    for (int k4 = 0; k4 < 25; ++k4) {
        const int k = k4 * 4;
        const float w0 = Ww[(k + 0) * H_ + j];
        const float w1 = Ww[(k + 1) * H_ + j];
        const float w2 = Ww[(k + 2) * H_ + j];
        const float w3 = Ww[(k + 3) * H_ + j];
#pragma unroll
        for (int r = 0; r < RPT; ++r) {
            const float4 h4 = ((const float4*)nod_s[rg * RPT + r])[k4];
            wa[r] = fmaf(h4.x, w0, wa[r]);
            wa[r] = fmaf(h4.y, w1, wa[r]);
            wa[r] = fmaf(h4.z, w2, wa[r]);
            wa[r] = fmaf(h4.w, w3, wa[r]);
        }
    }
#pragma unroll
    for (int r = 0; r < RPT; ++r)
        hw[(size_t)(row0 + rg * RPT + r) * H_ + j] = wa[r];
}

// ---------------------------------------------------------------------------
// K2: one fused message pass. NEW STRUCTURE (r1): 8 rows/block, 256 threads,
// thread (rg = t>>7, j = t&127) computes 4 rows (rg*4..rg*4+3) for column j.
// Rationale (rocprof r0): VALUBusy 45%, HBM 4% -> stalled on L1/L2 serving
// ~1 GB/dispatch of per-block weight re-streams (1 weight load per FMA for
// only 2 rows of reuse). Register-tiling 4 rows per thread cuts vmem request
// count 4x; total FMA count unchanged. ILP=4 acc chains hide load latency at
// the reduced occupancy (grid 512 -> 2 blocks/CU).
// Message loop: e_s b128 uniform broadcast + ballot-bit SGPR masks +
// coalesced hw load shared by 4 rows.
// MODE 1 -> tanh update + next-pass hv/hw projections; MODE 2 -> readout.
template <int MODE, int INIT_HV>
__global__ __launch_bounds__(256, 2) void k_pass(const float* __restrict__ edges,
                                                 const float* __restrict__ We,
                                                 const float* __restrict__ Wu,
                                                 const float* __restrict__ Wv,
                                                 const float* __restrict__ Ww,
                                                 const float* __restrict__ Wr,
                                                 const float* __restrict__ nodes,
                                                 float* __restrict__ hv_io,
                                                 const float* __restrict__ hw_in,
                                                 float* __restrict__ hw_out,
                                                 const float* __restrict__ hid_in,
                                                 float* __restrict__ hidden,
                                                 float* __restrict__ out) {
    __shared__ float4 e_s[RPB][N_];        // 16 KB
    __shared__ float  asum_s[RPB][2];      // per-half-row sums
    __shared__ unsigned qmask_s[RPB][4];   // per-row edge-mask bits (4x32)
    __shared__ float  hid_s[RPB][H_];
    __shared__ float  msg_s[RPB][H_];
    __shared__ float  hn_s[RPB][H_];
    __shared__ float  nod_s[RPB][H_];      // MODE 2 only
    __shared__ float  red_s[RPB][H_];      // MODE 2 only

    const int bx = blockIdx.x;
    const int b = bx >> 4;                 // 32 batches x 16 tiles
    const int vt = bx & 15;
    const int row0 = b * N_ + vt * RPB;

    const int t = threadIdx.x, rg = t >> 7, j = t & 127;
    const int wv = t >> 6, lane = t & 63;
    const bool act = (j < H_);

    {   // stage 8 rows' edges (1024 float4); ballot masks; half-row sums
        const float4* eg = (const float4*)(edges + (size_t)row0 * N_ * 4);
        float4* es = &e_s[0][0];
#pragma unroll
        for (int q = 0; q < 4; ++q) {
            const int idx = q * 256 + t;          // 0..1023, coalesced
            const float4 e = eg[idx];
            es[idx] = e;
            float s = (e.x + e.y) + (e.z + e.w);
            const unsigned long long bal = __ballot(s != 0.f);
            const int seg = q * 4 + wv;           // half-row id (wave-uniform)
            const int rowq = seg >> 1, half = seg & 1;
            if (lane == 0) {
                qmask_s[rowq][half * 2]     = (unsigned)bal;
                qmask_s[rowq][half * 2 + 1] = (unsigned)(bal >> 32);
            }
#pragma unroll
            for (int off = 32; off > 0; off >>= 1) s += __shfl_down(s, off);
            if (lane == 0) asum_s[rowq][half] = s;
        }
    }
    {   // stage pre-update hidden rows (8x25 float4); nodes too if readout
        const float4* hg = (const float4*)(hid_in + (size_t)row0 * H_);
        if (t < 200) ((float4*)hid_s)[t] = hg[t];
        if (MODE == 2) {
            const float4* ng = (const float4*)(nodes + (size_t)row0 * H_);
            if (t < 200) ((float4*)nod_s)[t] = ng[t];
        }
    }
    __syncthreads();

    float nm[RPT];
#pragma unroll
    for (int r = 0; r < RPT; ++r) {
        const int row = rg * RPT + r;
        nm[r] = ((asum_s[row][0] + asum_s[row][1]) != 0.f) ? 1.f : 0.f;
    }

    if (act) {
        float hv[RPT];
        if (INIT_HV) {      // pass 1: hv = hid @ Wv computed in-register
            float va[RPT] = {0.f, 0.f, 0.f, 0.f};
#pragma unroll 5
            for (int k4 = 0; k4 < 25; ++k4) {
                const int k = k4 * 4;
                const float w0 = Wv[(k + 0) * H_ + j];
                const float w1 = Wv[(k + 1) * H_ + j];
                const float w2 = Wv[(k + 2) * H_ + j];
                const float w3 = Wv[(k + 3) * H_ + j];
#pragma unroll
                for (int r = 0; r < RPT; ++r) {
                    const float4 h4 = ((const float4*)hid_s[rg * RPT + r])[k4];
                    va[r] = fmaf(h4.x, w0, va[r]);
                    va[r] = fmaf(h4.y, w1, va[r]);
                    va[r] = fmaf(h4.z, w2, va[r]);
                    va[r] = fmaf(h4.w, w3, va[r]);
                }
            }
#pragma unroll
            for (int r = 0; r < RPT; ++r) hv[r] = va[r];
        } else {
#pragma unroll
            for (int r = 0; r < RPT; ++r)
                hv[r] = hv_io[(size_t)(row0 + rg * RPT + r) * H_ + j];
        }
        const float we0 = We[0 * H_ + j], we1 = We[1 * H_ + j];
        const float we2 = We[2 * H_ + j], we3 = We[3 * H_ + j];
        const float* hwp = hw_in + (size_t)b * N_ * H_ + j;
        float acc[RPT] = {0.f, 0.f, 0.f, 0.f};
        for (int c = 0; c < 4; ++c) {             // 4 chunks of 32 w
            unsigned mq[RPT];
#pragma unroll
            for (int r = 0; r < RPT; ++r)
                mq[r] = __builtin_amdgcn_readfirstlane(qmask_s[rg * RPT + r][c]);
            const float* hc = hwp + (size_t)(c * 32) * H_;
#pragma unroll 8
            for (int w8 = 0; w8 < 32; ++w8) {
                const float hww = hc[w8 * H_];    // coalesced; shared by 4 rows
#pragma unroll
                for (int r = 0; r < RPT; ++r) {
                    const float4 e = e_s[rg * RPT + r][c * 32 + w8];  // broadcast
                    float p = hv[r] + hww;
                    p = fmaf(e.x, we0, p);
                    p = fmaf(e.y, we1, p);
                    p = fmaf(e.z, we2, p);
                    p = fmaf(e.w, we3, p);
                    const float m = ((mq[r] >> w8) & 1u) ? 1.f : 0.f;
                    acc[r] = fmaf(m, fmaxf(p, 0.f), acc[r]);
                }
            }
        }
#pragma unroll
        for (int r = 0; r < RPT; ++r) msg_s[rg * RPT + r][j] = acc[r];
    }
    __syncthreads();

    float nh[RPT];
    if (act) {
        float u[RPT] = {0.f, 0.f, 0.f, 0.f};
#pragma unroll 5
        for (int k4 = 0; k4 < 25; ++k4) {
            const int k = k4 * 4;
            const float w0 = Wu[(k + 0) * H_ + j];
            const float w1 = Wu[(k + 1) * H_ + j];
            const float w2 = Wu[(k + 2) * H_ + j];
            const float w3 = Wu[(k + 3) * H_ + j];
#pragma unroll
            for (int r = 0; r < RPT; ++r) {
                const float4 h4 = ((const float4*)hid_s[rg * RPT + r])[k4];
                u[r] = fmaf(h4.x, w0, u[r]);
                u[r] = fmaf(h4.y, w1, u[r]);
                u[r] = fmaf(h4.z, w2, u[r]);
                u[r] = fmaf(h4.w, w3, u[r]);
            }
        }
#pragma unroll 5
        for (int k4 = 0; k4 < 25; ++k4) {
            const int k = H_ + k4 * 4;
            const float w0 = Wu[(k + 0) * H_ + j];
            const float w1 = Wu[(k + 1) * H_ + j];
            const float w2 = Wu[(k + 2) * H_ + j];
            const float w3 = Wu[(k + 3) * H_ + j];
#pragma unroll
            for (int r = 0; r < RPT; ++r) {
                const float4 m4 = ((const float4*)msg_s[rg * RPT + r])[k4];
                u[r] = fmaf(m4.x, w0, u[r]);
                u[r] = fmaf(m4.y, w1, u[r]);
                u[r] = fmaf(m4.z, w2, u[r]);
                u[r] = fmaf(m4.w, w3, u[r]);
            }
        }
#pragma unroll
        for (int r = 0; r < RPT; ++r) {
            const int row = rg * RPT + r;
            nh[r] = (nm[r] != 0.f) ? tanhf(u[r]) : hid_s[row][j];
            hn_s[row][j] = nh[r];
            if (MODE == 1) hidden[(size_t)(row0 + row) * H_ + j] = nh[r];
        }
    }
    __syncthreads();

    if (MODE == 1) {        // next pass's hv/hw from fresh hidden (own rows)
        if (act) {
            float va[RPT] = {0.f, 0.f, 0.f, 0.f};
            float wa[RPT] = {0.f, 0.f, 0.f, 0.f};
#pragma unroll 5
            for (int k4 = 0; k4 < 25; ++k4) {
                const int k = k4 * 4;
                const float v0 = Wv[(k + 0) * H_ + j], q0 = Ww[(k + 0) * H_ + j];
                const float v1 = Wv[(k + 1) * H_ + j], q1 = Ww[(k + 1) * H_ + j];
                const float v2 = Wv[(k + 2) * H_ + j], q2 = Ww[(k + 2) * H_ + j];
                const float v3 = Wv[(k + 3) * H_ + j], q3 = Ww[(k + 3) * H_ + j];
#pragma unroll
                for (int r = 0; r < RPT; ++r) {
                    const float4 h4 = ((const float4*)hn_s[rg * RPT + r])[k4];
                    va[r] = fmaf(h4.x, v0, va[r]);
                    wa[r] = fmaf(h4.x, q0, wa[r]);
                    va[r] = fmaf(h4.y, v1, va[r]);
                    wa[r] = fmaf(h4.y, q1, wa[r]);
                    va[r] = fmaf(h4.z, v2, va[r]);
                    wa[r] = fmaf(h4.z, q2, wa[r]);
                    va[r] = fmaf(h4.w, v3, va[r]);
                    wa[r] = fmaf(h4.w, q3, wa[r]);
                }
            }
#pragma unroll
            for (int r = 0; r < RPT; ++r) {
                const size_t g = (size_t)(row0 + rg * RPT + r) * H_ + j;
                hv_io[g] = va[r];     // row-local: safe in-place
                hw_out[g] = wa[r];    // double-buffered
            }
        }
    } else {                // MODE 2: fused readout
        if (act) {
            float u[RPT] = {0.f, 0.f, 0.f, 0.f};
#pragma unroll 5
            for (int k4 = 0; k4 < 25; ++k4) {
                const int k = k4 * 4;
                const float w0 = Wr[(k + 0) * H_ + j];
                const float w1 = Wr[(k + 1) * H_ + j];
                const float w2 = Wr[(k + 2) * H_ + j];
                const float w3 = Wr[(k + 3) * H_ + j];
#pragma unroll
                for (int r = 0; r < RPT; ++r) {
                    const float4 h4 = ((const float4*)hn_s[rg * RPT + r])[k4];
                    u[r] = fmaf(h4.x, w0, u[r]);
                    u[r] = fmaf(h4.y, w1, u[r]);
                    u[r] = fmaf(h4.z, w2, u[r]);
                    u[r] = fmaf(h4.w, w3, u[r]);
                }
            }
#pragma unroll 5
            for (int k4 = 0; k4 < 25; ++k4) {
                const int k = H_ + k4 * 4;
                const float w0 = Wr[(k + 0) * H_ + j];
                const float w1 = Wr[(k + 1) * H_ + j];
                const float w2 = Wr[(k + 2) * H_ + j];
                const float w3 = Wr[(k + 3) * H_ + j];
#pragma unroll
                for (int r = 0; r < RPT; ++r) {
                    const float4 n4 = ((const float4*)nod_s[rg * RPT + r])[k4];
                    u[r] = fmaf(n4.x, w0, u[r]);
                    u[r] = fmaf(n4.y, w1, u[r]);
                    u[r] = fmaf(n4.z, w2, u[r]);
                    u[r] = fmaf(n4.w, w3, u[r]);
                }
            }
#pragma unroll
            for (int r = 0; r < RPT; ++r)
                red_s[rg * RPT + r][j] = nm[r] * fmaxf(u[r], 0.f);
        }
        __syncthreads();
        if (t < H_) {
            float ssum = 0.f;
#pragma unroll
            for (int rr = 0; rr < RPB; ++rr) ssum += red_s[rr][t];
            atomicAdd(out + b * H_ + t, ssum);
        }
    }
}

// ---------------------------------------------------------------------------
extern "C" void kernel_launch(void* const* d_in, const int* in_sizes, int n_in,
                              void* d_out, int out_size, void* d_ws, size_t ws_size,
                              hipStream_t stream) {
    const float* nodes = (const float*)d_in[0];
    const float* edges = (const float*)d_in[1];
    const float* Wv    = (const float*)d_in[2];
    const float* Ww    = (const float*)d_in[3];
    const float* We    = (const float*)d_in[4];
    const float* Wu    = (const float*)d_in[5];
    const float* Wr    = (const float*)d_in[6];
    float* out = (float*)d_out;

    float* hidden = (float*)d_ws;     // RH
    float* hv     = hidden + RH;      // RH
    float* hwA    = hv + RH;          // RH
    float* hwB    = hwA + RH;         // RH

    k_proj0<<<ROWS / RPB, 256, 0, stream>>>(nodes, Ww, hwA, out);

    k_pass<1, 1><<<ROWS / RPB, 256, 0, stream>>>(edges, We, Wu, Wv, Ww, Wr, nodes,
                                                 hv, hwA, hwB, nodes, hidden, out);
    k_pass<1, 0><<<ROWS / RPB, 256, 0, stream>>>(edges, We, Wu, Wv, Ww, Wr, nodes,
                                                 hv, hwB, hwA, hidden, hidden, out);
    k_pass<2, 0><<<ROWS / RPB, 256, 0, stream>>>(edges, We, Wu, Wv, Ww, Wr, nodes,
                                                 hv, hwA, hwB, hidden, hidden, out);
}

// Round 3
// 214.123 us; speedup vs baseline: 1.1177x; 1.1177x over previous
//
#include <hip/hip_runtime.h>
#include <math.h>

#define B_   32
#define N_   128
#define H_   100
#define ROWS (B_ * N_)    // 4096
#define RH   (ROWS * H_)  // 409600
#define OUTSZ (B_ * H_)   // 3200
#define CK   20           // k-rows per staged weight chunk
#define CK4  (CK * H_ / 4)  // float4 per chunk = 500

// ---------------------------------------------------------------------------
// K1: hw = nodes@Ww ONLY (initial hv computed in-register by pass 1).
// Also zero-initializes out. (unchanged from the 192us baseline)
__global__ __launch_bounds__(256, 6) void k_proj0(const float* __restrict__ nodes,
                                                  const float* __restrict__ Ww,
                                                  float* __restrict__ hw,
                                                  float* __restrict__ out) {
    __shared__ float nod_s[2][H_];
    const int row0 = blockIdx.x * 2;
    const int t = threadIdx.x, r = t >> 7, j = t & 127;
    {   // zero out[] (3 dispatches before any atomicAdd; stream-ordered)
        const int gid = blockIdx.x * 256 + t;
        if (gid < OUTSZ) out[gid] = 0.f;
    }
    {
        const float4* ng = (const float4*)(nodes + (size_t)row0 * H_);
        if (t < 50) ((float4*)nod_s)[t] = ng[t];
    }
    __syncthreads();
    if (j >= H_) return;
    const float4* h4p = (const float4*)nod_s[r];
    float wa = 0.f;
#pragma unroll 5
    for (int k4 = 0; k4 < 25; ++k4) {
        const float4 h4 = h4p[k4];
        const int k = k4 * 4;
        wa = fmaf(h4.x, Ww[(k + 0) * H_ + j], wa);
        wa = fmaf(h4.y, Ww[(k + 1) * H_ + j], wa);
        wa = fmaf(h4.z, Ww[(k + 2) * H_ + j], wa);
        wa = fmaf(h4.w, Ww[(k + 3) * H_ + j], wa);
    }
    hw[(size_t)(row0 + r) * H_ + j] = wa;
}

// ---------------------------------------------------------------------------
// Stage one 20x100 weight chunk (8 KB) into LDS; all 256 threads, coalesced.
__device__ __forceinline__ void stage_chunk(float4* dst, const float* W,
                                            int k0, int t) {
    const float4* src = (const float4*)(W + (size_t)k0 * H_);
    dst[t] = src[t];
    if (t < CK4 - 256) dst[256 + t] = src[256 + t];
}

// ---------------------------------------------------------------------------
// K2: one fused message pass. r0 structure (2 rows/block, batch-affine
// swizzle, ballot-mask message loop) + NEW (r2): chunked double-buffered LDS
// staging of GEMM weights. Rationale: r0 counters showed VALUBusy 45%,
// HBM 4%, conflicts 0 -> the 55% stall is L2 latency on per-wave weight
// streams (Wu/Wv/Ww working sets 40-80 KB >> 32 KB L1, VGPR=32 limits load
// depth). Staging converts them to bulk prefetched float4 loads + stride-1
// ds_read_b32 (2-way bank aliasing = free). w4_s[2] rotates seamlessly
// across phases (update -> proj_va -> proj_wa / readout), always staging
// chunk c+1 while computing chunk c.
// r1 lesson: occupancy >> request count; this version RAISES occupancy
// (LDS 22.5 KB -> 7 blocks/CU = 28 waves, launch_bounds(256,7)).
template <int MODE, int INIT_HV>
__global__ __launch_bounds__(256, 7) void k_pass(const float* __restrict__ edges,
                                                 const float* __restrict__ We,
                                                 const float* __restrict__ Wu,
                                                 const float* __restrict__ Wv,
                                                 const float* __restrict__ Ww,
                                                 const float* __restrict__ Wr,
                                                 const float* __restrict__ nodes,
                                                 float* __restrict__ hv_io,
                                                 const float* __restrict__ hw_in,
                                                 float* __restrict__ hw_out,
                                                 const float* __restrict__ hid_in,
                                                 float* __restrict__ hidden,
                                                 float* __restrict__ out) {
    __shared__ float4 e_s[2][N_];          // 4 KB
    __shared__ float  asum_part[4];        // per-wave partial row sums
    __shared__ unsigned qmask_s[2][4];     // per-row edge-mask bits (4x32)
    __shared__ float  hid_s[2][H_];
    __shared__ float  msg_s[2][H_];
    __shared__ float  hn_s[2][H_];
    __shared__ float  nod_s[MODE == 2 ? 2 : 1][MODE == 2 ? H_ : 1]; // MODE2 only
    __shared__ float4 w4_s[2][CK4];        // 16 KB: double-buffered weight chunk
    // MODE2's red_s overlays w4_s[0] after the last readout chunk (buf0 free
    // after the c==8 sync) -> keeps LDS at 7 blocks/CU.

    // batch-affine swizzle: co-resident blocks (≡ mod 256) share batch b
    const int bx = blockIdx.x;
    const int cu = bx & 255, slot = bx >> 8;
    const int b = cu >> 3;
    const int vt = (cu & 7) + slot * 8;
    const int row0 = b * N_ + vt * 2;

    const int t = threadIdx.x, r = t >> 7, j = t & 127;
    const int wv = t >> 6, lane = t & 63;
    const int row = row0 + r;
    const bool act = (j < H_);

    {   // stage both rows' edges; ballot edge-mask bits; reduce row sums
        const float4* eg = (const float4*)(edges + (size_t)row0 * N_ * 4);
        const float4 e = eg[t];                   // t == r*128 + j, coalesced
        e_s[r][j] = e;
        float s = (e.x + e.y) + (e.z + e.w);
        const unsigned long long bal = __ballot(s != 0.f);
        if (lane == 0) {
            qmask_s[wv >> 1][(wv & 1) * 2]     = (unsigned)bal;
            qmask_s[wv >> 1][(wv & 1) * 2 + 1] = (unsigned)(bal >> 32);
        }
#pragma unroll
        for (int off = 32; off > 0; off >>= 1) s += __shfl_down(s, off);
        if (lane == 0) asum_part[wv] = s;
    }
    {   // stage pre-update hidden rows (50 float4); nodes too if readout pass
        const float4* hg = (const float4*)(hid_in + (size_t)row0 * H_);
        if (t < 50) ((float4*)hid_s)[t] = hg[t];
        if (MODE == 2) {
            const float4* ng = (const float4*)(nodes + (size_t)row0 * H_);
            if (t < 50) ((float4*)nod_s)[t] = ng[t];
        }
    }
    // prefetch Wu chunk 0 into buf0; message loop hides the latency
    stage_chunk(w4_s[0], Wu, 0, t);
    __syncthreads();

    const float nm = ((asum_part[2 * r] + asum_part[2 * r + 1]) != 0.f) ? 1.f : 0.f;

    if (act) {
        float hvv;
        if (INIT_HV) {      // pass 1: hv = hid @ Wv computed in-register
            const float4* h4p = (const float4*)hid_s[r];
            float va = 0.f;
#pragma unroll 5
            for (int k4 = 0; k4 < 25; ++k4) {
                const float4 h4 = h4p[k4];
                const int k = k4 * 4;
                va = fmaf(h4.x, Wv[(k + 0) * H_ + j], va);
                va = fmaf(h4.y, Wv[(k + 1) * H_ + j], va);
                va = fmaf(h4.z, Wv[(k + 2) * H_ + j], va);
                va = fmaf(h4.w, Wv[(k + 3) * H_ + j], va);
            }
            hvv = va;
        } else {
            hvv = hv_io[(size_t)row * H_ + j];
        }
        const float we0 = We[0 * H_ + j], we1 = We[1 * H_ + j];
        const float we2 = We[2 * H_ + j], we3 = We[3 * H_ + j];
        const float* hwp = hw_in + (size_t)b * N_ * H_ + j;
        float acc = 0.f;
        for (int c = 0; c < 4; ++c) {             // 4 chunks of 32 w
            const unsigned mq =
                __builtin_amdgcn_readfirstlane(qmask_s[r][c]);  // SGPR, uniform
            const float4* ec = &e_s[r][c * 32];
            const float*  hc = hwp + (size_t)(c * 32) * H_;
#pragma unroll 8
            for (int w8 = 0; w8 < 32; ++w8) {
                const float4 e = ec[w8];          // LDS b128 broadcast
                const float  hww = hc[w8 * H_];   // coalesced; L1-hot w/ swizzle
                const float  m = ((mq >> w8) & 1u) ? 1.f : 0.f;  // SALU cselect
                float p = hvv + hww;
                p = fmaf(e.x, we0, p);
                p = fmaf(e.y, we1, p);
                p = fmaf(e.z, we2, p);
                p = fmaf(e.w, we3, p);
                acc = fmaf(m, fmaxf(p, 0.f), acc);
            }
        }
        msg_s[r][j] = acc;
    }
    __syncthreads();

    // ---- update GEMM: u = [hid|msg] @ Wu, Wu streamed through LDS chunks ----
    int cur = 0;
    float u0 = 0.f, u1 = 0.f;
    for (int c = 0; c < 10; ++c) {
        if (c < 9)       stage_chunk(w4_s[cur ^ 1], Wu, (c + 1) * CK, t);
        else if (MODE == 1) stage_chunk(w4_s[cur ^ 1], Wv, 0, t);   // proj va chunk0
        else             stage_chunk(w4_s[cur ^ 1], Wr, 0, t);       // readout chunk0
        if (act) {
            const float* wb = (const float*)w4_s[cur] + j;
            const float4* hb = (c < 5) ? ((const float4*)hid_s[r]) + c * 5
                                       : ((const float4*)msg_s[r]) + (c - 5) * 5;
#pragma unroll
            for (int k4 = 0; k4 < 5; ++k4) {
                const float4 h4 = hb[k4];
                const float* wr_ = wb + k4 * 4 * H_;
                u0 = fmaf(h4.x, wr_[0 * H_], u0);
                u1 = fmaf(h4.y, wr_[1 * H_], u1);
                u0 = fmaf(h4.z, wr_[2 * H_], u0);
                u1 = fmaf(h4.w, wr_[3 * H_], u1);
            }
        }
        __syncthreads();
        cur ^= 1;
    }
    // cur == 0 here; next phase's chunk0 sits in buf0.

    if (act) {
        const float nh = (nm != 0.f) ? tanhf(u0 + u1) : hid_s[r][j];
        hn_s[r][j] = nh;
        if (MODE == 1) hidden[(size_t)row * H_ + j] = nh;
    }
    __syncthreads();

    if (MODE == 1) {        // next pass's hv then hw from fresh hidden
        float a0 = 0.f, a1 = 0.f;
        for (int c = 0; c < 5; ++c) {             // Wv chunks
            if (c < 4) stage_chunk(w4_s[cur ^ 1], Wv, (c + 1) * CK, t);
            else       stage_chunk(w4_s[cur ^ 1], Ww, 0, t);
            if (act) {
                const float* wb = (const float*)w4_s[cur] + j;
                const float4* hb = ((const float4*)hn_s[r]) + c * 5;
#pragma unroll
                for (int k4 = 0; k4 < 5; ++k4) {
                    const float4 h4 = hb[k4];
                    const float* wr_ = wb + k4 * 4 * H_;
                    a0 = fmaf(h4.x, wr_[0 * H_], a0);
                    a1 = fmaf(h4.y, wr_[1 * H_], a1);
                    a0 = fmaf(h4.z, wr_[2 * H_], a0);
                    a1 = fmaf(h4.w, wr_[3 * H_], a1);
                }
            }
            __syncthreads();
            cur ^= 1;
        }
        if (act) hv_io[(size_t)row * H_ + j] = a0 + a1;   // row-local in-place
        float b0 = 0.f, b1 = 0.f;
        for (int c = 0; c < 5; ++c) {             // Ww chunks
            if (c < 4) stage_chunk(w4_s[cur ^ 1], Ww, (c + 1) * CK, t);
            if (act) {
                const float* wb = (const float*)w4_s[cur] + j;
                const float4* hb = ((const float4*)hn_s[r]) + c * 5;
#pragma unroll
                for (int k4 = 0; k4 < 5; ++k4) {
                    const float4 h4 = hb[k4];
                    const float* wr_ = wb + k4 * 4 * H_;
                    b0 = fmaf(h4.x, wr_[0 * H_], b0);
                    b1 = fmaf(h4.y, wr_[1 * H_], b1);
                    b0 = fmaf(h4.z, wr_[2 * H_], b0);
                    b1 = fmaf(h4.w, wr_[3 * H_], b1);
                }
            }
            if (c < 4) __syncthreads();
            cur ^= 1;
        }
        if (act) hw_out[(size_t)row * H_ + j] = b0 + b1;  // double-buffered
    } else {                // MODE 2: fused readout, Wr through LDS chunks
        float a0 = 0.f, a1 = 0.f;
        for (int c = 0; c < 10; ++c) {
            if (c < 9) stage_chunk(w4_s[cur ^ 1], Wr, (c + 1) * CK, t);
            if (act) {
                const float* wb = (const float*)w4_s[cur] + j;
                const float4* hb = (c < 5) ? ((const float4*)hn_s[r]) + c * 5
                                           : ((const float4*)nod_s[r]) + (c - 5) * 5;
#pragma unroll
                for (int k4 = 0; k4 < 5; ++k4) {
                    const float4 h4 = hb[k4];
                    const float* wr_ = wb + k4 * 4 * H_;
                    a0 = fmaf(h4.x, wr_[0 * H_], a0);
                    a1 = fmaf(h4.y, wr_[1 * H_], a1);
                    a0 = fmaf(h4.z, wr_[2 * H_], a0);
                    a1 = fmaf(h4.w, wr_[3 * H_], a1);
                }
            }
            __syncthreads();
            cur ^= 1;
        }
        // red overlay on w4_s[0]: buf0's last readers finished at c==8 sync
        float* red = (float*)w4_s[0];
        if (act) red[r * H_ + j] = nm * fmaxf(a0 + a1, 0.f);
        __syncthreads();
        if (t < H_) atomicAdd(out + b * H_ + t, red[0 * H_ + t] + red[1 * H_ + t]);
    }
}

// ---------------------------------------------------------------------------
extern "C" void kernel_launch(void* const* d_in, const int* in_sizes, int n_in,
                              void* d_out, int out_size, void* d_ws, size_t ws_size,
                              hipStream_t stream) {
    const float* nodes = (const float*)d_in[0];
    const float* edges = (const float*)d_in[1];
    const float* Wv    = (const float*)d_in[2];
    const float* Ww    = (const float*)d_in[3];
    const float* We    = (const float*)d_in[4];
    const float* Wu    = (const float*)d_in[5];
    const float* Wr    = (const float*)d_in[6];
    float* out = (float*)d_out;

    float* hidden = (float*)d_ws;     // RH
    float* hv     = hidden + RH;      // RH
    float* hwA    = hv + RH;          // RH
    float* hwB    = hwA + RH;         // RH

    k_proj0<<<ROWS / 2, 256, 0, stream>>>(nodes, Ww, hwA, out);

    k_pass<1, 1><<<ROWS / 2, 256, 0, stream>>>(edges, We, Wu, Wv, Ww, Wr, nodes,
                                               hv, hwA, hwB, nodes, hidden, out);
    k_pass<1, 0><<<ROWS / 2, 256, 0, stream>>>(edges, We, Wu, Wv, Ww, Wr, nodes,
                                               hv, hwB, hwA, hidden, hidden, out);
    k_pass<2, 0><<<ROWS / 2, 256, 0, stream>>>(edges, We, Wu, Wv, Ww, Wr, nodes,
                                               hv, hwA, hwB, hidden, hidden, out);
}

// Round 4
// 197.054 us; speedup vs baseline: 1.2145x; 1.0866x over previous
//
#include <hip/hip_runtime.h>
#include <math.h>

#define B_   32
#define N_   128
#define H_   100
#define ROWS (B_ * N_)    // 4096
#define RH   (ROWS * H_)  // 409600
#define OUTSZ (B_ * H_)   // 3200
#define RPB  8            // rows per block (k_pass)

// ---------------------------------------------------------------------------
// K1: hw = nodes@Ww ONLY (initial hv computed in-register by pass 1).
// Also zero-initializes out. (unchanged from the 192us baseline)
__global__ __launch_bounds__(256, 6) void k_proj0(const float* __restrict__ nodes,
                                                  const float* __restrict__ Ww,
                                                  float* __restrict__ hw,
                                                  float* __restrict__ out) {
    __shared__ float nod_s[2][H_];
    const int row0 = blockIdx.x * 2;
    const int t = threadIdx.x, r = t >> 7, j = t & 127;
    {   // zero out[] (3 dispatches before any atomicAdd; stream-ordered)
        const int gid = blockIdx.x * 256 + t;
        if (gid < OUTSZ) out[gid] = 0.f;
    }
    {
        const float4* ng = (const float4*)(nodes + (size_t)row0 * H_);
        if (t < 50) ((float4*)nod_s)[t] = ng[t];
    }
    __syncthreads();
    if (j >= H_) return;
    const float4* h4p = (const float4*)nod_s[r];
    float wa = 0.f;
#pragma unroll 5
    for (int k4 = 0; k4 < 25; ++k4) {
        const float4 h4 = h4p[k4];
        const int k = k4 * 4;
        wa = fmaf(h4.x, Ww[(k + 0) * H_ + j], wa);
        wa = fmaf(h4.y, Ww[(k + 1) * H_ + j], wa);
        wa = fmaf(h4.z, Ww[(k + 2) * H_ + j], wa);
        wa = fmaf(h4.w, Ww[(k + 3) * H_ + j], wa);
    }
    hw[(size_t)(row0 + r) * H_ + j] = wa;
}

// ---------------------------------------------------------------------------
// K2 (r3 structure): 1024 threads, 8 rows/block, grid 512 = 2 blocks/CU
// (32 waves/CU). Per-thread work identical to the proven r0 kernel
// (1 row x 1 column; direct global weight loads -- r2 falsified the weight
// theory). NEW: the whole 51.2 KB hw[b] slab is staged ONCE per block into
// LDS, converting the message loop's 128 latency-exposed global loads/thread
// (the dominant stall by elimination) into conflict-free ds_read_b32
// (stride-100 rows -> consecutive banks, 2-way aliasing = free).
// LDS ~77 KB/block -> exactly 2 blocks/CU. MODE 2 overlays nodes/red onto
// the dead e_s region after the message loop to stay within budget.
template <int MODE, int INIT_HV>
__global__ __launch_bounds__(1024, 8) void k_pass(const float* __restrict__ edges,
                                                  const float* __restrict__ We,
                                                  const float* __restrict__ Wu,
                                                  const float* __restrict__ Wv,
                                                  const float* __restrict__ Ww,
                                                  const float* __restrict__ Wr,
                                                  const float* __restrict__ nodes,
                                                  float* __restrict__ hv_io,
                                                  const float* __restrict__ hw_in,
                                                  float* __restrict__ hw_out,
                                                  const float* __restrict__ hid_in,
                                                  float* __restrict__ hidden,
                                                  float* __restrict__ out) {
    __shared__ float  hw_s[N_ * H_];       // 51.2 KB: full batch hw slab
    __shared__ float4 e_s[RPB * N_];       // 16 KB; MODE2: overlaid after msg loop
    __shared__ float  asum_s[RPB][2];      // per-half-row edge sums
    __shared__ unsigned qmask_s[RPB][4];   // per-row edge-mask bits (4x32)
    __shared__ float  hid_s[RPB][H_];
    __shared__ float  msg_s[RPB][H_];
    __shared__ float  hn_s[RPB][H_];

    // batch-affine swizzle: co-resident blocks (≡ mod 256) share batch b
    const int bx = blockIdx.x;             // grid = 512
    const int cu = bx & 255, slot = bx >> 8;
    const int b = cu >> 3;
    const int vt = (cu & 7) + slot * 8;    // 0..15
    const int row0 = b * N_ + vt * RPB;

    const int t = threadIdx.x;
    const int rg = t >> 7, j = t & 127;    // row-group 0..7, column lane
    const int wv = t >> 6, lane = t & 63;  // wave 0..15
    const int row = row0 + rg;
    const bool act = (j < H_);

    {   // stage full hw[b] slab: 3200 float4, coalesced
        const float4* src = (const float4*)(hw_in + (size_t)b * N_ * H_);
        float4* dst = (float4*)hw_s;
        dst[t] = src[t];
        dst[1024 + t] = src[1024 + t];
        dst[2048 + t] = src[2048 + t];
        if (t < 128) dst[3072 + t] = src[3072 + t];
    }
    {   // stage 8 rows' edges (1024 float4); ballot masks; half-row sums
        const float4* eg = (const float4*)(edges + (size_t)row0 * N_ * 4);
        const float4 e = eg[t];            // t == row*128 + w, coalesced
        e_s[t] = e;
        float s = (e.x + e.y) + (e.z + e.w);
        const unsigned long long bal = __ballot(s != 0.f);
        const int rowq = wv >> 1, half = wv & 1;   // wave-uniform
        if (lane == 0) {
            qmask_s[rowq][half * 2]     = (unsigned)bal;
            qmask_s[rowq][half * 2 + 1] = (unsigned)(bal >> 32);
        }
#pragma unroll
        for (int off = 32; off > 0; off >>= 1) s += __shfl_down(s, off);
        if (lane == 0) asum_s[rowq][half] = s;
    }
    {   // stage pre-update hidden rows (8 x 25 float4)
        const float4* hg = (const float4*)(hid_in + (size_t)row0 * H_);
        if (t < 200) ((float4*)hid_s)[t] = hg[t];
    }
    __syncthreads();

    const float nm = ((asum_s[rg][0] + asum_s[rg][1]) != 0.f) ? 1.f : 0.f;

    if (act) {
        float hvv;
        if (INIT_HV) {      // pass 1: hv = hid @ Wv computed in-register
            const float4* h4p = (const float4*)hid_s[rg];
            float va = 0.f;
#pragma unroll 5
            for (int k4 = 0; k4 < 25; ++k4) {
                const float4 h4 = h4p[k4];
                const int k = k4 * 4;
                va = fmaf(h4.x, Wv[(k + 0) * H_ + j], va);
                va = fmaf(h4.y, Wv[(k + 1) * H_ + j], va);
                va = fmaf(h4.z, Wv[(k + 2) * H_ + j], va);
                va = fmaf(h4.w, Wv[(k + 3) * H_ + j], va);
            }
            hvv = va;
        } else {
            hvv = hv_io[(size_t)row * H_ + j];
        }
        const float we0 = We[0 * H_ + j], we1 = We[1 * H_ + j];
        const float we2 = We[2 * H_ + j], we3 = We[3 * H_ + j];
        const float* hwp = hw_s + j;       // LDS column pointer
        float acc = 0.f;
        for (int c = 0; c < 4; ++c) {      // 4 chunks of 32 w
            const unsigned mq =
                __builtin_amdgcn_readfirstlane(qmask_s[rg][c]);  // SGPR, uniform
            const float4* ec = &e_s[rg * N_ + c * 32];
            const float*  hc = hwp + (size_t)(c * 32) * H_;
#pragma unroll 8
            for (int w8 = 0; w8 < 32; ++w8) {
                const float4 e = ec[w8];          // LDS b128 broadcast
                const float  hww = hc[w8 * H_];   // LDS b32, conflict-free
                const float  m = ((mq >> w8) & 1u) ? 1.f : 0.f;  // SALU cselect
                float p = hvv + hww;
                p = fmaf(e.x, we0, p);
                p = fmaf(e.y, we1, p);
                p = fmaf(e.z, we2, p);
                p = fmaf(e.w, we3, p);
                acc = fmaf(m, fmaxf(p, 0.f), acc);
            }
        }
        msg_s[rg][j] = acc;
    }
    __syncthreads();

    if (MODE == 2) {        // e_s dead: stage original nodes into its overlay
        float* nodf = (float*)e_s + 1024;  // floats 1024..1823 of e_s region
        const float4* ng = (const float4*)(nodes + (size_t)row0 * H_);
        if (t < 200) ((float4*)nodf)[t] = ng[t];
        // the post-update barrier below orders these writes before their reads
    }

    if (act) {
        const float4* h4p = (const float4*)hid_s[rg];
        const float4* m4p = (const float4*)msg_s[rg];
        float u = 0.f;
#pragma unroll 5
        for (int k4 = 0; k4 < 25; ++k4) {
            const float4 h4 = h4p[k4];
            const int k = k4 * 4;
            u = fmaf(h4.x, Wu[(k + 0) * H_ + j], u);
            u = fmaf(h4.y, Wu[(k + 1) * H_ + j], u);
            u = fmaf(h4.z, Wu[(k + 2) * H_ + j], u);
            u = fmaf(h4.w, Wu[(k + 3) * H_ + j], u);
        }
#pragma unroll 5
        for (int k4 = 0; k4 < 25; ++k4) {
            const float4 m4 = m4p[k4];
            const int k = H_ + k4 * 4;
            u = fmaf(m4.x, Wu[(k + 0) * H_ + j], u);
            u = fmaf(m4.y, Wu[(k + 1) * H_ + j], u);
            u = fmaf(m4.z, Wu[(k + 2) * H_ + j], u);
            u = fmaf(m4.w, Wu[(k + 3) * H_ + j], u);
        }
        const float nh = (nm != 0.f) ? tanhf(u) : hid_s[rg][j];
        hn_s[rg][j] = nh;
        if (MODE == 1) hidden[(size_t)row * H_ + j] = nh;
    }
    __syncthreads();

    if (MODE == 1) {        // next pass's hv/hw from fresh hidden (own rows)
        if (act) {
            const float4* h4p = (const float4*)hn_s[rg];
            float va = 0.f, wa = 0.f;
#pragma unroll 5
            for (int k4 = 0; k4 < 25; ++k4) {
                const float4 h4 = h4p[k4];
                const int k = k4 * 4;
                va = fmaf(h4.x, Wv[(k + 0) * H_ + j], va);
                wa = fmaf(h4.x, Ww[(k + 0) * H_ + j], wa);
                va = fmaf(h4.y, Wv[(k + 1) * H_ + j], va);
                wa = fmaf(h4.y, Ww[(k + 1) * H_ + j], wa);
                va = fmaf(h4.z, Wv[(k + 2) * H_ + j], va);
                wa = fmaf(h4.z, Ww[(k + 2) * H_ + j], wa);
                va = fmaf(h4.w, Wv[(k + 3) * H_ + j], va);
                wa = fmaf(h4.w, Ww[(k + 3) * H_ + j], wa);
            }
            hv_io[(size_t)row * H_ + j] = va;     // row-local: safe in-place
            hw_out[(size_t)row * H_ + j] = wa;    // double-buffered
        }
    } else {                // MODE 2: fused readout
        float* nodf = (float*)e_s + 1024;
        float* redf = (float*)e_s;                // floats 0..799 (disjoint)
        if (act) {
            const float4* h4p = (const float4*)hn_s[rg];
            const float4* n4p = (const float4*)(nodf + rg * H_);
            float u = 0.f;
#pragma unroll 5
            for (int k4 = 0; k4 < 25; ++k4) {
                const float4 h4 = h4p[k4];
                const int k = k4 * 4;
                u = fmaf(h4.x, Wr[(k + 0) * H_ + j], u);
                u = fmaf(h4.y, Wr[(k + 1) * H_ + j], u);
                u = fmaf(h4.z, Wr[(k + 2) * H_ + j], u);
                u = fmaf(h4.w, Wr[(k + 3) * H_ + j], u);
            }
#pragma unroll 5
            for (int k4 = 0; k4 < 25; ++k4) {
                const float4 n4 = n4p[k4];
                const int k = H_ + k4 * 4;
                u = fmaf(n4.x, Wr[(k + 0) * H_ + j], u);
                u = fmaf(n4.y, Wr[(k + 1) * H_ + j], u);
                u = fmaf(n4.z, Wr[(k + 2) * H_ + j], u);
                u = fmaf(n4.w, Wr[(k + 3) * H_ + j], u);
            }
            redf[rg * H_ + j] = nm * fmaxf(u, 0.f);
        }
        __syncthreads();
        if (t < H_) {
            float ssum = 0.f;
#pragma unroll
            for (int rr = 0; rr < RPB; ++rr) ssum += redf[rr * H_ + t];
            atomicAdd(out + b * H_ + t, ssum);
        }
    }
}

// ---------------------------------------------------------------------------
extern "C" void kernel_launch(void* const* d_in, const int* in_sizes, int n_in,
                              void* d_out, int out_size, void* d_ws, size_t ws_size,
                              hipStream_t stream) {
    const float* nodes = (const float*)d_in[0];
    const float* edges = (const float*)d_in[1];
    const float* Wv    = (const float*)d_in[2];
    const float* Ww    = (const float*)d_in[3];
    const float* We    = (const float*)d_in[4];
    const float* Wu    = (const float*)d_in[5];
    const float* Wr    = (const float*)d_in[6];
    float* out = (float*)d_out;

    float* hidden = (float*)d_ws;     // RH
    float* hv     = hidden + RH;      // RH
    float* hwA    = hv + RH;          // RH
    float* hwB    = hwA + RH;         // RH

    k_proj0<<<ROWS / 2, 256, 0, stream>>>(nodes, Ww, hwA, out);

    k_pass<1, 1><<<ROWS / RPB, 1024, 0, stream>>>(edges, We, Wu, Wv, Ww, Wr, nodes,
                                                  hv, hwA, hwB, nodes, hidden, out);
    k_pass<1, 0><<<ROWS / RPB, 1024, 0, stream>>>(edges, We, Wu, Wv, Ww, Wr, nodes,
                                                  hv, hwB, hwA, hidden, hidden, out);
    k_pass<2, 0><<<ROWS / RPB, 1024, 0, stream>>>(edges, We, Wu, Wv, Ww, Wr, nodes,
                                                  hv, hwA, hwB, hidden, hidden, out);
}